// Round 4
// baseline (2231.875 us; speedup 1.0000x reference)
//
#include <hip/hip_runtime.h>

#define T_STEPS 32
#define BATCH   65536
#define IN_DIM  27
#define INP     28          // W_ih rows padded to 28 floats (16B-aligned)
#define H_DIM   10
#define HP      12          // W_hh rows padded to 12 floats (16B-aligned)
#define G_DIM   40          // 4*H
#define H2_DIM  5
#define EPB     128         // batch elements per 256-thread block (2 threads/elem)

__device__ __forceinline__ float fast_exp2(float v) { return __builtin_amdgcn_exp2f(v); }
__device__ __forceinline__ float fast_rcp(float v)  { return __builtin_amdgcn_rcpf(v); }
// sigmoid(v) = rcp(1 + exp2(-v*log2(e)))
__device__ __forceinline__ float fast_sigmoid(float v) {
    return fast_rcp(1.f + fast_exp2(v * -1.4426950408889634f));
}
// tanh(v) = 1 - 2*rcp(exp2(2v*log2(e)) + 1); saturates correctly at +/-inf
__device__ __forceinline__ float fast_tanh(float v) {
    return 1.f - 2.f * fast_rcp(1.f + fast_exp2(v * 2.8853900817779268f));
}

// Fused LSTM: 2 threads per batch element. Thread q in {0,1} of a lane pair
// owns hidden units [q*5, q*5+5): it computes the 20 gate rows (i,f,g,o x 5)
// and the elementwise update for those units, then swaps its 5 h values with
// its partner via shfl_xor. This halves the per-step serial VALU path vs
// 1-thread/elem AND doubles occupancy to 2 waves/SIMD (the recurrence finally
// has TLP to hide LDS/global latency). Weights live in LDS; every weight read
// is a 2-address broadcast (q=0 rows vs q=1 rows) -> conflict-free.
__global__ __launch_bounds__(256, 2) void lstm_fused2_kernel(
    const float* __restrict__ word,   // [T, B, IN]
    const float* __restrict__ W_ih,   // [4H, IN]
    const float* __restrict__ W_hh,   // [4H, H]
    const float* __restrict__ b_ih,   // [4H]
    const float* __restrict__ b_hh,   // [4H]
    const float* __restrict__ W_fc,   // [H2, H]
    const float* __restrict__ b_fc,   // [H2]
    const float* __restrict__ W_out,  // [1, H2]
    const float* __restrict__ b_out,  // [1]
    float* __restrict__ out)          // [B]
{
    __shared__ float s_wih[G_DIM * INP];   // 4480 B
    __shared__ float s_whh[G_DIM * HP];    // 1920 B

    const int tid = threadIdx.x;

    // ---- stage padded weights in LDS (once) ----
    for (int idx = tid; idx < G_DIM * INP; idx += 256) {
        const int j = idx / INP, k = idx - j * INP;
        s_wih[idx] = (k < IN_DIM) ? W_ih[j * IN_DIM + k] : 0.f;
    }
    for (int idx = tid; idx < G_DIM * HP; idx += 256) {
        const int j = idx / HP, k = idx - j * HP;
        s_whh[idx] = (k < H_DIM) ? W_hh[j * H_DIM + k] : 0.f;
    }
    __syncthreads();   // only barrier in the kernel

    const int q  = tid & 1;                 // which half of the units I own
    const int e  = blockIdx.x * EPB + (tid >> 1);   // my batch element
    const int u0 = q * 5;                   // first owned unit

    // biases for my 20 gate rows (read once)
    float bias_r[4][5];
#pragma unroll
    for (int g = 0; g < 4; ++g)
#pragma unroll
        for (int j = 0; j < 5; ++j) {
            const int row = g * H_DIM + u0 + j;
            bias_r[g][j] = b_ih[row] + b_hh[row];
        }

    // full h (padded to 12 for float4 h-gemv), my 5 c values
    float hf[HP];
#pragma unroll
    for (int m = 0; m < HP; ++m) hf[m] = 0.f;
    float cm[5];
#pragma unroll
    for (int j = 0; j < 5; ++j) cm[j] = 0.f;

    // x for t=0 (padded slot 27 stays 0 forever)
    float x[INP];
    {
        const float* xp = word + (size_t)e * IN_DIM;
#pragma unroll
        for (int k = 0; k < IN_DIM; ++k) x[k] = xp[k];
        x[IN_DIM] = 0.f;
    }

    const size_t t_stride = (size_t)BATCH * IN_DIM;
    const float* my_wih = s_wih + u0 * INP;   // rows u0.. (static offsets below)
    const float* my_whh = s_whh + u0 * HP;

#pragma unroll 2
    for (int t = 0; t < T_STEPS; ++t) {
        // ---- prefetch next step's x (consumed at loop bottom; ~1900 cyc of
        //      compute in between hides the ~900 cyc load latency) ----
        float xn[IN_DIM];
        {
            const int tn = (t + 1 < T_STEPS) ? (t + 1) : t;
            const float* xq = word + (size_t)tn * t_stride + (size_t)e * IN_DIM;
#pragma unroll
            for (int k = 0; k < IN_DIM; ++k) xn[k] = xq[k];
        }

        // ---- gates for my 20 rows: x-part then h-part, float4 LDS reads ----
        float acc[4][5];
#pragma unroll
        for (int g = 0; g < 4; ++g)
#pragma unroll
            for (int j = 0; j < 5; ++j) {
                float a = bias_r[g][j];
                const float* w = my_wih + (g * H_DIM + j) * INP;
#pragma unroll
                for (int k = 0; k < INP; k += 4) {
                    const float4 qv = *(const float4*)(w + k);
                    a = fmaf(qv.x, x[k    ], a);
                    a = fmaf(qv.y, x[k + 1], a);
                    a = fmaf(qv.z, x[k + 2], a);
                    a = fmaf(qv.w, x[k + 3], a);
                }
                acc[g][j] = a;
            }
#pragma unroll
        for (int g = 0; g < 4; ++g)
#pragma unroll
            for (int j = 0; j < 5; ++j) {
                float a = acc[g][j];
                const float* w = my_whh + (g * H_DIM + j) * HP;
#pragma unroll
                for (int k = 0; k < HP; k += 4) {
                    const float4 qv = *(const float4*)(w + k);
                    a = fmaf(qv.x, hf[k    ], a);
                    a = fmaf(qv.y, hf[k + 1], a);
                    a = fmaf(qv.z, hf[k + 2], a);
                    a = fmaf(qv.w, hf[k + 3], a);
                }
                acc[g][j] = a;
            }

        // ---- elementwise update for my 5 units ----
        float hm[5];
#pragma unroll
        for (int j = 0; j < 5; ++j) {
            const float iv = fast_sigmoid(acc[0][j]);
            const float fv = fast_sigmoid(acc[1][j]);
            const float gv = fast_tanh   (acc[2][j]);
            const float ov = fast_sigmoid(acc[3][j]);
            const float cn = fmaf(fv, cm[j], iv * gv);
            const float hv = ov * fast_tanh(cn);
            hm[j] = fmaxf(hv, 0.f);   // reference ReLUs both carries
            cm[j] = fmaxf(cn, 0.f);
        }

        // ---- swap my 5 h values with partner; rebuild full h[10] ----
#pragma unroll
        for (int j = 0; j < 5; ++j) {
            const float ho = __shfl_xor(hm[j], 1);
            hf[j]     = q ? ho    : hm[j];   // v_cndmask, static indices
            hf[5 + j] = q ? hm[j] : ho;
        }

        // ---- rotate prefetched x ----
#pragma unroll
        for (int k = 0; k < IN_DIM; ++k) x[k] = xn[k];
    }

    // ---- head (once; lane q==0 of each pair writes) ----
    if (q == 0) {
        float acc = b_out[0];
#pragma unroll
        for (int p = 0; p < H2_DIM; ++p) {
            float y = b_fc[p];
            const float* wf = W_fc + p * H_DIM;
#pragma unroll
            for (int m = 0; m < H_DIM; ++m) y = fmaf(wf[m], hf[m], y);
            y = fmaxf(y, 0.f);
            acc = fmaf(W_out[p], y, acc);
        }
        out[e] = fast_sigmoid(acc);
    }
}

extern "C" void kernel_launch(void* const* d_in, const int* in_sizes, int n_in,
                              void* d_out, int out_size, void* d_ws, size_t ws_size,
                              hipStream_t stream) {
    const float* word  = (const float*)d_in[0];
    const float* W_ih  = (const float*)d_in[1];
    const float* W_hh  = (const float*)d_in[2];
    const float* b_ih  = (const float*)d_in[3];
    const float* b_hh  = (const float*)d_in[4];
    const float* W_fc  = (const float*)d_in[5];
    const float* b_fc  = (const float*)d_in[6];
    const float* W_out = (const float*)d_in[7];
    const float* b_out = (const float*)d_in[8];
    float* out = (float*)d_out;

    // 2 threads/elem: 256-thread block covers 128 elems -> 512 blocks
    // = 2 blocks/CU resident = 8 waves/CU = 2 waves/SIMD.
    lstm_fused2_kernel<<<BATCH / EPB, 256, 0, stream>>>(
        word, W_ih, W_hh, b_ih, b_hh, W_fc, b_fc, W_out, b_out, out);
}

// Round 5
// 230.479 us; speedup vs baseline: 9.6836x; 9.6836x over previous
//
#include <hip/hip_runtime.h>

#define T_STEPS 32
#define BATCH   65536
#define IN_DIM  27
#define INP     28          // W_ih rows padded to 28 floats (16B-aligned)
#define H_DIM   10
#define G_DIM   40          // 4*H
#define H2_DIM  5

__device__ __forceinline__ float fast_exp2(float v) { return __builtin_amdgcn_exp2f(v); }
__device__ __forceinline__ float fast_rcp(float v)  { return __builtin_amdgcn_rcpf(v); }
__device__ __forceinline__ float fast_sigmoid(float v) {
    return fast_rcp(1.f + fast_exp2(v * -1.4426950408889634f));
}
__device__ __forceinline__ float fast_tanh(float v) {
    return 1.f - 2.f * fast_rcp(1.f + fast_exp2(v * 2.8853900817779268f));
}

// ---------------------------------------------------------------------------
// Pass 1 (unchanged from R3, measured ~115us vs ~89us floor):
// gates_x[t][j][b] = x[t,b,:] @ W_ih[j,:] + b_ih[j] + b_hh[j], layout [T][4H][B]
// ---------------------------------------------------------------------------
__global__ __launch_bounds__(256) void input_proj_kernel(
    const float* __restrict__ word,   // [T, B, IN]
    const float* __restrict__ W_ih,   // [4H, IN]
    const float* __restrict__ b_ih,   // [4H]
    const float* __restrict__ b_hh,   // [4H]
    float* __restrict__ gx)           // [T, 4H, B]
{
    __shared__ float s_x[256 * IN_DIM];
    __shared__ float s_w[G_DIM * INP];
    __shared__ float s_b[G_DIM];

    const int tid = threadIdx.x;
    const int t   = blockIdx.y;
    const int b0  = blockIdx.x * 256;

    const float* src = word + ((size_t)t * BATCH + b0) * IN_DIM;
#pragma unroll
    for (int i = 0; i < IN_DIM; ++i) s_x[tid + 256 * i] = src[tid + 256 * i];

    for (int idx = tid; idx < G_DIM * INP; idx += 256) {
        const int j = idx / INP, k = idx - j * INP;
        s_w[idx] = (k < IN_DIM) ? W_ih[j * IN_DIM + k] : 0.f;
    }
    if (tid < G_DIM) s_b[tid] = b_ih[tid] + b_hh[tid];
    __syncthreads();

    float xr[INP];
#pragma unroll
    for (int k = 0; k < IN_DIM; ++k) xr[k] = s_x[tid * IN_DIM + k];
    xr[IN_DIM] = 0.f;

    float* dst = gx + (size_t)t * G_DIM * BATCH + (size_t)(b0 + tid);
#pragma unroll
    for (int j = 0; j < G_DIM; j += 2) {
        float a0 = s_b[j], a1 = s_b[j + 1];
        const float* w0 = s_w + j * INP;
        const float* w1 = w0 + INP;
#pragma unroll
        for (int k = 0; k < INP; k += 4) {
            const float4 q0 = *(const float4*)(w0 + k);
            const float4 q1 = *(const float4*)(w1 + k);
            a0 = fmaf(q0.x, xr[k], fmaf(q0.y, xr[k+1], fmaf(q0.z, xr[k+2], fmaf(q0.w, xr[k+3], a0))));
            a1 = fmaf(q1.x, xr[k], fmaf(q1.y, xr[k+1], fmaf(q1.z, xr[k+2], fmaf(q1.w, xr[k+3], a1))));
        }
        dst[(size_t)j * BATCH]       = a0;
        dst[(size_t)(j + 1) * BATCH] = a1;
    }
}

// ---------------------------------------------------------------------------
// Pass 2 v2: 4 threads/elem. Thread r owns gate-type r (rows r*10..r*10+9):
// its W_hh slice (100 floats) lives in VGPRs -> zero in-loop LDS. Quad
// exchange of activated gates via __shfl_xor 1/2/3 (DPP, in-quad). All lanes
// decode roles (8 cndmask/unit) and redundantly compute the valid update, so
// h and c stay correct in every lane. amdgpu_waves_per_eu(2,2) pins the
// register budget at 256 so the allocator cannot spill chasing 4 waves (R4).
// ---------------------------------------------------------------------------
__global__
__attribute__((amdgpu_flat_work_group_size(256, 256), amdgpu_waves_per_eu(2, 2)))
void recurrence4_kernel(
    const float* __restrict__ gx,     // [T, 4H, B]
    const float* __restrict__ W_hh,   // [4H, H]
    const float* __restrict__ W_fc,   // [H2, H]
    const float* __restrict__ b_fc,   // [H2]
    const float* __restrict__ W_out,  // [1, H2]
    const float* __restrict__ b_out,  // [1]
    float* __restrict__ out)          // [B]
{
    const int tid = threadIdx.x;
    const int r   = tid & 3;                       // owned gate type: 0=i 1=f 2=g 3=o
    const int e   = blockIdx.x * 64 + (tid >> 2);  // batch element

    // my 10 W_hh rows -> registers (one-time; 4-address broadcast per inst)
    float wh[10][10];
    {
        const float* wsrc = W_hh + (size_t)(r * 10) * H_DIM;
#pragma unroll
        for (int j = 0; j < 10; ++j)
#pragma unroll
            for (int n = 0; n < 10; ++n) wh[j][n] = wsrc[j * H_DIM + n];
    }

    // per-lane activation formula: type 2 (g) is tanh, others sigmoid
    const bool  is_tanh = (r == 2);
    const float kexp    = is_tanh ? 2.8853900817779268f : -1.4426950408889634f;
    const bool  m1 = (r & 1) != 0;
    const bool  m2 = (r & 2) != 0;

    float h[H_DIM], c[H_DIM];
#pragma unroll
    for (int m = 0; m < H_DIM; ++m) { h[m] = 0.f; c[m] = 0.f; }

    // per-lane gx base: rows r*10..r*10+9, column e
    const float* gbase = gx + (size_t)(r * 10) * BATCH + e;

    // t=0 gates (x-part; bias already folded in pass 1)
    float cur[10];
#pragma unroll
    for (int j = 0; j < 10; ++j) cur[j] = gbase[(size_t)j * BATCH];

    for (int t = 0; t < T_STEPS; ++t) {
        // ---- prefetch next step's rows (coalesced: 4x 64B segments/inst) ----
        float nxt[10];
        {
            const int tn = (t + 1 < T_STEPS) ? (t + 1) : t;
            const float* gp = gbase + (size_t)tn * G_DIM * BATCH;
#pragma unroll
            for (int j = 0; j < 10; ++j) nxt[j] = gp[(size_t)j * BATCH];
        }

        // ---- h-part (weights from VGPR) + my activation per owned row ----
        float act[10];
#pragma unroll
        for (int j = 0; j < 10; ++j) {
            float a = cur[j];
#pragma unroll
            for (int n = 0; n < H_DIM; ++n) a = fmaf(wh[j][n], h[n], a);
            const float e2 = fast_exp2(a * kexp);
            const float u  = fast_rcp(1.f + e2);
            act[j] = is_tanh ? fmaf(-2.f, u, 1.f) : u;
        }

        // ---- quad all-gather + role decode + update (valid in ALL lanes) ----
#pragma unroll
        for (int m = 0; m < H_DIM; ++m) {
            const float s  = act[m];
            const float x1 = __shfl_xor(s, 1);
            const float x2 = __shfl_xor(s, 2);
            const float x3 = __shfl_xor(s, 3);
            // source holding type X sits at lane r^ (r xor X-map); decode:
            const float tA  = m1 ? x1 : s;    // {s,x1} half
            const float tB  = m1 ? x3 : x2;   // {x2,x3} half
            const float tAp = m1 ? s  : x1;
            const float tBp = m1 ? x2 : x3;
            const float iv = m2 ? tB  : tA;   // type 0
            const float fv = m2 ? tBp : tAp;  // type 1
            const float gv = m2 ? tA  : tB;   // type 2 (tanh'd)
            const float ov = m2 ? tAp : tBp;  // type 3
            const float cn = fmaf(fv, c[m], iv * gv);
            const float hv = ov * fast_tanh(cn);
            h[m] = fmaxf(hv, 0.f);   // reference ReLUs both carries
            c[m] = fmaxf(cn, 0.f);
        }

#pragma unroll
        for (int j = 0; j < 10; ++j) cur[j] = nxt[j];
    }

    // ---- head: one lane per quad ----
    if (r == 0) {
        float acc = b_out[0];
#pragma unroll
        for (int p = 0; p < H2_DIM; ++p) {
            float y = b_fc[p];
            const float* wf = W_fc + p * H_DIM;
#pragma unroll
            for (int m = 0; m < H_DIM; ++m) y = fmaf(wf[m], h[m], y);
            y = fmaxf(y, 0.f);
            acc = fmaf(W_out[p], y, acc);
        }
        out[e] = fast_sigmoid(acc);
    }
}

// ---------------------------------------------------------------------------
// Fallback (fused, known-correct) if workspace is too small for gates_x.
// ---------------------------------------------------------------------------
__global__ __launch_bounds__(256, 1) void lstm_word_fused_kernel(
    const float* __restrict__ word, const float* __restrict__ W_ih,
    const float* __restrict__ W_hh, const float* __restrict__ b_ih,
    const float* __restrict__ b_hh, const float* __restrict__ W_fc,
    const float* __restrict__ b_fc, const float* __restrict__ W_out,
    const float* __restrict__ b_out, float* __restrict__ out)
{
    const int b = blockIdx.x * blockDim.x + threadIdx.x;
    float bias[G_DIM];
#pragma unroll
    for (int j = 0; j < G_DIM; ++j) bias[j] = b_ih[j] + b_hh[j];
    float h[H_DIM], c[H_DIM];
#pragma unroll
    for (int m = 0; m < H_DIM; ++m) { h[m] = 0.f; c[m] = 0.f; }
    const size_t t_stride = (size_t)BATCH * IN_DIM;
    const size_t row_off  = (size_t)b * IN_DIM;
    float x[IN_DIM];
    {
        const float* xp = word + row_off;
#pragma unroll
        for (int k = 0; k < IN_DIM; ++k) x[k] = xp[k];
    }
    for (int t = 0; t < T_STEPS; ++t) {
        float xn[IN_DIM];
        {
            const int tn = (t + 1 < T_STEPS) ? (t + 1) : t;
            const float* xq = word + (size_t)tn * t_stride + row_off;
#pragma unroll
            for (int k = 0; k < IN_DIM; ++k) xn[k] = xq[k];
        }
        float hn[H_DIM];
#pragma unroll
        for (int m = 0; m < H_DIM; ++m) {
            float ai = bias[m], af = bias[m + H_DIM], ag = bias[m + 2*H_DIM], ao = bias[m + 3*H_DIM];
            const float* wi = W_ih + m * IN_DIM;
            const float* wf = W_ih + (m + H_DIM) * IN_DIM;
            const float* wg = W_ih + (m + 2*H_DIM) * IN_DIM;
            const float* wo = W_ih + (m + 3*H_DIM) * IN_DIM;
#pragma unroll
            for (int k = 0; k < IN_DIM; ++k) {
                const float xv = x[k];
                ai = fmaf(wi[k], xv, ai); af = fmaf(wf[k], xv, af);
                ag = fmaf(wg[k], xv, ag); ao = fmaf(wo[k], xv, ao);
            }
            const float* hi = W_hh + m * H_DIM;
            const float* hf = W_hh + (m + H_DIM) * H_DIM;
            const float* hg = W_hh + (m + 2*H_DIM) * H_DIM;
            const float* ho = W_hh + (m + 3*H_DIM) * H_DIM;
#pragma unroll
            for (int n = 0; n < H_DIM; ++n) {
                const float hv = h[n];
                ai = fmaf(hi[n], hv, ai); af = fmaf(hf[n], hv, af);
                ag = fmaf(hg[n], hv, ag); ao = fmaf(ho[n], hv, ao);
            }
            const float iv = fast_sigmoid(ai), fv = fast_sigmoid(af);
            const float gv = fast_tanh(ag),    ov = fast_sigmoid(ao);
            const float cn = fmaf(fv, c[m], iv * gv);
            const float hv = ov * fast_tanh(cn);
            hn[m] = fmaxf(hv, 0.f);
            c[m]  = fmaxf(cn, 0.f);
        }
#pragma unroll
        for (int m = 0; m < H_DIM; ++m) h[m] = hn[m];
#pragma unroll
        for (int k = 0; k < IN_DIM; ++k) x[k] = xn[k];
    }
    float acc = b_out[0];
#pragma unroll
    for (int p = 0; p < H2_DIM; ++p) {
        float y = b_fc[p];
        const float* wf = W_fc + p * H_DIM;
#pragma unroll
        for (int m = 0; m < H_DIM; ++m) y = fmaf(wf[m], h[m], y);
        y = fmaxf(y, 0.f);
        acc = fmaf(W_out[p], y, acc);
    }
    out[b] = fast_sigmoid(acc);
}

extern "C" void kernel_launch(void* const* d_in, const int* in_sizes, int n_in,
                              void* d_out, int out_size, void* d_ws, size_t ws_size,
                              hipStream_t stream) {
    const float* word  = (const float*)d_in[0];
    const float* W_ih  = (const float*)d_in[1];
    const float* W_hh  = (const float*)d_in[2];
    const float* b_ih  = (const float*)d_in[3];
    const float* b_hh  = (const float*)d_in[4];
    const float* W_fc  = (const float*)d_in[5];
    const float* b_fc  = (const float*)d_in[6];
    const float* W_out = (const float*)d_in[7];
    const float* b_out = (const float*)d_in[8];
    float* out = (float*)d_out;

    const size_t need = (size_t)T_STEPS * G_DIM * BATCH * sizeof(float); // 335.5 MB
    if (ws_size >= need) {
        float* gxbuf = (float*)d_ws;
        dim3 grid1(BATCH / 256, T_STEPS);
        input_proj_kernel<<<grid1, 256, 0, stream>>>(word, W_ih, b_ih, b_hh, gxbuf);
        // 4 threads/elem: 65536*4 = 262144 threads -> 1024 blocks
        recurrence4_kernel<<<BATCH / 64, 256, 0, stream>>>(
            gxbuf, W_hh, W_fc, b_fc, W_out, b_out, out);
    } else {
        lstm_word_fused_kernel<<<BATCH / 256, 256, 0, stream>>>(
            word, W_ih, W_hh, b_ih, b_hh, W_fc, b_fc, W_out, b_out, out);
    }
}